// Round 1
// baseline (428.117 us; speedup 1.0000x reference)
//
#include <hip/hip_runtime.h>

// One thread per row of 8 floats.
// midv = 4th-smallest (ascending index 3) via 19-comparator sorting network.
// mask = x > midv (strict top-4). out = softmax(x) * mask.
// Memory-bound: 512 MiB total HBM traffic, floor ~85us @ 6.3 TB/s.

#define CMPSWAP(i, j)                     \
    {                                     \
        float lo = fminf(x[i], x[j]);     \
        float hi = fmaxf(x[i], x[j]);     \
        x[i] = lo;                        \
        x[j] = hi;                        \
    }

__global__ __launch_bounds__(256) void HNet3_topk_softmax_kernel(
    const float4* __restrict__ in, float4* __restrict__ out, int nrows)
{
    int row = blockIdx.x * blockDim.x + threadIdx.x;
    if (row >= nrows) return;

    float4 a = in[2 * row];
    float4 b = in[2 * row + 1];

    float v[8] = {a.x, a.y, a.z, a.w, b.x, b.y, b.z, b.w};
    float x[8];
#pragma unroll
    for (int i = 0; i < 8; ++i) x[i] = v[i];

    // Optimal 8-element sorting network (19 comparators).
    CMPSWAP(0, 1) CMPSWAP(2, 3) CMPSWAP(4, 5) CMPSWAP(6, 7)
    CMPSWAP(0, 2) CMPSWAP(1, 3) CMPSWAP(4, 6) CMPSWAP(5, 7)
    CMPSWAP(1, 2) CMPSWAP(5, 6) CMPSWAP(0, 4) CMPSWAP(3, 7)
    CMPSWAP(1, 5) CMPSWAP(2, 6)
    CMPSWAP(1, 4) CMPSWAP(3, 6)
    CMPSWAP(2, 4) CMPSWAP(3, 5)
    CMPSWAP(3, 4)

    float midv = x[3];  // 4th-smallest == 5th-largest
    float m    = x[7];  // row max (free from the sort) for stable softmax

    float e[8];
    float s = 0.f;
#pragma unroll
    for (int i = 0; i < 8; ++i) {
        e[i] = __expf(v[i] - m);
        s += e[i];
    }
    float inv = __builtin_amdgcn_rcpf(s);  // v_rcp_f32, ~1 ulp — fine for 2e-2 threshold

    float4 oa, ob;
    oa.x = (v[0] > midv) ? e[0] * inv : 0.f;
    oa.y = (v[1] > midv) ? e[1] * inv : 0.f;
    oa.z = (v[2] > midv) ? e[2] * inv : 0.f;
    oa.w = (v[3] > midv) ? e[3] * inv : 0.f;
    ob.x = (v[4] > midv) ? e[4] * inv : 0.f;
    ob.y = (v[5] > midv) ? e[5] * inv : 0.f;
    ob.z = (v[6] > midv) ? e[6] * inv : 0.f;
    ob.w = (v[7] > midv) ? e[7] * inv : 0.f;

    out[2 * row]     = oa;
    out[2 * row + 1] = ob;
}

extern "C" void kernel_launch(void* const* d_in, const int* in_sizes, int n_in,
                              void* d_out, int out_size, void* d_ws, size_t ws_size,
                              hipStream_t stream) {
    const float* in = (const float*)d_in[0];
    float* out      = (float*)d_out;

    // num_per_group is fixed at 8 in setup_inputs(); kernel hardcodes it.
    int nrows   = in_sizes[0] / 8;
    int threads = 256;
    int blocks  = (nrows + threads - 1) / threads;

    HNet3_topk_softmax_kernel<<<blocks, threads, 0, stream>>>(
        (const float4*)in, (float4*)out, nrows);
}

// Round 2
// 424.017 us; speedup vs baseline: 1.0097x; 1.0097x over previous
//
#include <hip/hip_runtime.h>

// One thread per row of 8 floats.
// midv = 4th-smallest (ascending index 3) via 19-comparator sorting network.
// mask = x > midv (strict top-4). out = softmax(x) * mask.
// Memory-bound streaming kernel: 512 MiB total HBM traffic, zero reuse ->
// non-temporal loads/stores to skip cache allocation. Floor ~85us @ 6.3 TB/s.

typedef float f32x4 __attribute__((ext_vector_type(4)));

#define CMPSWAP(i, j)                     \
    {                                     \
        float lo = fminf(x[i], x[j]);     \
        float hi = fmaxf(x[i], x[j]);     \
        x[i] = lo;                        \
        x[j] = hi;                        \
    }

__global__ __launch_bounds__(256) void HNet3_topk_softmax_kernel(
    const f32x4* __restrict__ in, f32x4* __restrict__ out, int nrows)
{
    int row = blockIdx.x * blockDim.x + threadIdx.x;
    if (row >= nrows) return;

    f32x4 a = __builtin_nontemporal_load(in + 2 * row);
    f32x4 b = __builtin_nontemporal_load(in + 2 * row + 1);

    float v[8] = {a[0], a[1], a[2], a[3], b[0], b[1], b[2], b[3]};
    float x[8];
#pragma unroll
    for (int i = 0; i < 8; ++i) x[i] = v[i];

    // Optimal 8-element sorting network (19 comparators).
    CMPSWAP(0, 1) CMPSWAP(2, 3) CMPSWAP(4, 5) CMPSWAP(6, 7)
    CMPSWAP(0, 2) CMPSWAP(1, 3) CMPSWAP(4, 6) CMPSWAP(5, 7)
    CMPSWAP(1, 2) CMPSWAP(5, 6) CMPSWAP(0, 4) CMPSWAP(3, 7)
    CMPSWAP(1, 5) CMPSWAP(2, 6)
    CMPSWAP(1, 4) CMPSWAP(3, 6)
    CMPSWAP(2, 4) CMPSWAP(3, 5)
    CMPSWAP(3, 4)

    float midv = x[3];  // 4th-smallest == 5th-largest
    float m    = x[7];  // row max (free from the sort) for stable softmax

    float e[8];
    float s = 0.f;
#pragma unroll
    for (int i = 0; i < 8; ++i) {
        e[i] = __expf(v[i] - m);
        s += e[i];
    }
    float inv = __builtin_amdgcn_rcpf(s);  // v_rcp_f32, ~1 ulp

    f32x4 oa, ob;
    oa[0] = (v[0] > midv) ? e[0] * inv : 0.f;
    oa[1] = (v[1] > midv) ? e[1] * inv : 0.f;
    oa[2] = (v[2] > midv) ? e[2] * inv : 0.f;
    oa[3] = (v[3] > midv) ? e[3] * inv : 0.f;
    ob[0] = (v[4] > midv) ? e[4] * inv : 0.f;
    ob[1] = (v[5] > midv) ? e[5] * inv : 0.f;
    ob[2] = (v[6] > midv) ? e[6] * inv : 0.f;
    ob[3] = (v[7] > midv) ? e[7] * inv : 0.f;

    __builtin_nontemporal_store(oa, out + 2 * row);
    __builtin_nontemporal_store(ob, out + 2 * row + 1);
}

extern "C" void kernel_launch(void* const* d_in, const int* in_sizes, int n_in,
                              void* d_out, int out_size, void* d_ws, size_t ws_size,
                              hipStream_t stream) {
    const f32x4* in = (const f32x4*)d_in[0];
    f32x4* out      = (f32x4*)d_out;

    // num_per_group is fixed at 8 in setup_inputs(); kernel hardcodes it.
    int nrows   = in_sizes[0] / 8;
    int threads = 256;
    int blocks  = (nrows + threads - 1) / threads;

    HNet3_topk_softmax_kernel<<<blocks, threads, 0, stream>>>(in, out, nrows);
}